// Round 12
// baseline (243.872 us; speedup 1.0000x reference)
//
#include <hip/hip_runtime.h>

typedef __bf16 bf16;
typedef bf16 bf16x8 __attribute__((ext_vector_type(8)));
typedef bf16 bf16x4 __attribute__((ext_vector_type(4)));
typedef bf16 bf16x2 __attribute__((ext_vector_type(2)));
typedef float f32x4 __attribute__((ext_vector_type(4)));
typedef float f32x16 __attribute__((ext_vector_type(16)));
typedef int i32x4 __attribute__((ext_vector_type(4)));

#define XSZ 4194304   // 4096*1024 elements (B*S x D)
#define WSZ 1048576   // 1024*1024
#define KDIM 1024
// 0.125 * log2(e): fold 1/sqrt(dk) AND the exp->exp2 conversion into W_q
#define QSCALE 0.1803368801111137f

// ---------- helpers ----------
__device__ __forceinline__ void async16(const bf16* g, bf16* l) {
  __builtin_amdgcn_global_load_lds(
      (const __attribute__((address_space(1))) unsigned int*)g,
      (__attribute__((address_space(3))) unsigned int*)l, 16, 0, 0);
}

__device__ __forceinline__ bf16x8 ld16(const bf16* p) {  // one ds_read_b128 (16B-aligned)
  return __builtin_bit_cast(bf16x8, *(const i32x4*)p);
}

__device__ __forceinline__ f32x4 mfma16(bf16x8 a, bf16x8 b, f32x4 c) {
  return __builtin_amdgcn_mfma_f32_16x16x32_bf16(a, b, c, 0, 0, 0);
}
__device__ __forceinline__ f32x16 mfma32(bf16x8 a, bf16x8 b, f32x16 c) {
  return __builtin_amdgcn_mfma_f32_32x32x16_bf16(a, b, c, 0, 0, 0);
}

__device__ __forceinline__ int packbf2(float lo, float hi) {
  bf16x2 t; t[0] = (bf16)lo; t[1] = (bf16)hi;
  return __builtin_bit_cast(int, t);
}

// exp2f without fast-math lowers to the accurate OCML software routine (~25 VALU
// instr). v_exp_f32 is 1-ulp, plenty for bf16.
__device__ __forceinline__ float fast_exp2(float x) {
#if __has_builtin(__builtin_amdgcn_exp2f)
  return __builtin_amdgcn_exp2f(x);
#else
  return exp2f(x);
#endif
}

// NOTE (R10): permlane32_swap half-broadcast misrouted data (absmax 0.19) —
// keep the proven shfl_xor+cndmask P-exchange.
// NOTE (R11): __launch_bounds__ 2nd arg behaves as BLOCKS/CU on this toolchain:
// VGPR cap = 2048 / (blocks * waves_per_block).
// NOTE (R15): attn staging = global_load_lds + both-sides XOR swizzle + 64-key
// subtile dbuf, one barrier/subtile: attn 73-76us, VGPR 60. BEST — KEPT.
// NOTE (R17): padded reg-staged attn killed all bank conflicts (4.19M->0) yet
// REGRESSED — conflicts were NOT critical-path. Counter size != bottleneck.
// NOTE (R19): 32-key subtiles REGRESSED: attn occupancy is GRID-limited (512
// blocks = 2/CU); raising LDS cap can't help. occupancy = min(grid/CU, LDS,
// VGPR): check grid FIRST.
// NOTE (R21): proj_gemm is the largest kernel (~90-100us by subtraction, only
// ~3 waves/SIMD: grid 768 = 3 blocks/CU binding). Tile 128x128 -> 64x128:
// grid (8,64,3) = 1536 = 6/CU avail, launch_bounds (256,5) -> 5 blocks/CU,
// 5 waves/SIMD, VGPR cap 102 (est ~80). Same BK=32 2-phase core, same K-order
// -> bit-identical. Tripwire: proj WRITE_SIZE growth = spills = revert.
// NOTE (R16/R18): proj/out GEMM = T3 2-phase dbuf at BK=32. KEPT.

// ---------- fused fp32 -> bf16 cast for all 7 tensors (dsts contiguous in ws) ----------
__global__ __launch_bounds__(256) void cast_all(const float* __restrict__ Xq, const float* __restrict__ Xk,
                                                const float* __restrict__ Xv, const float* __restrict__ Wq,
                                                const float* __restrict__ Wk, const float* __restrict__ Wv,
                                                const float* __restrict__ Wo, bf16* __restrict__ dst) {
  size_t i = ((size_t)blockIdx.x * 256 + threadIdx.x) * 8;
  const float* src; size_t off; float scale = 1.0f;
  if (i < XSZ)                { src = Xq; off = i; }
  else if (i < 2 * (size_t)XSZ) { src = Xk; off = i - XSZ; }
  else if (i < 3 * (size_t)XSZ) { src = Xv; off = i - 2 * (size_t)XSZ; }
  else if (i < 3 * (size_t)XSZ + WSZ) { src = Wq; off = i - 3 * (size_t)XSZ; scale = QSCALE; }
  else if (i < 3 * (size_t)XSZ + 2 * (size_t)WSZ) { src = Wk; off = i - 3 * (size_t)XSZ - WSZ; }
  else if (i < 3 * (size_t)XSZ + 3 * (size_t)WSZ) { src = Wv; off = i - 3 * (size_t)XSZ - 2 * (size_t)WSZ; }
  else                        { src = Wo; off = i - 3 * (size_t)XSZ - 3 * (size_t)WSZ; }
  float4 a = *(const float4*)(src + off);
  float4 b = *(const float4*)(src + off + 4);
  bf16x8 o;
  o[0] = (bf16)(a.x * scale); o[1] = (bf16)(a.y * scale);
  o[2] = (bf16)(a.z * scale); o[3] = (bf16)(a.w * scale);
  o[4] = (bf16)(b.x * scale); o[5] = (bf16)(b.y * scale);
  o[6] = (bf16)(b.z * scale); o[7] = (bf16)(b.w * scale);
  *(bf16x8*)(dst + i) = o;
}

// ---------- fused Q/K/V projection: 64x128 tiles, BK=32 2-phase dbuf ----------
// grid (8, 64, 3) = 1536 blocks; 5 blocks/CU (launch_bounds) -> 5 waves/SIMD.
// Per block: C[64x128] = A[64 rows,:] . W[128 rows,:]^T. LDS 24 KB (2 bufs x
// (A 4KB + B 8KB)). Wave tile 32x64, acc[2][4].
__global__ __launch_bounds__(256, 5) void proj_gemm(const bf16* __restrict__ xq, const bf16* __restrict__ xk,
                                                 const bf16* __restrict__ xv, const bf16* __restrict__ wq,
                                                 const bf16* __restrict__ wk, const bf16* __restrict__ wv,
                                                 bf16* __restrict__ Qo, bf16* __restrict__ Ko,
                                                 bf16* __restrict__ Vo) {
  __shared__ __align__(16) bf16 lds[2 * 6144];   // 24 KB
  const int z = blockIdx.z;
  const bf16* A = (z == 0) ? xq : (z == 1) ? xk : xv;
  const bf16* W = (z == 0) ? wq : (z == 1) ? wk : wv;
  bf16* C = (z == 0) ? Qo : (z == 1) ? Ko : Vo;
  const int t = threadIdx.x;
  const int lane = t & 63, wave = t >> 6;
  const int wm = wave & 1, wn = wave >> 1;
  const int quad = lane >> 4, m16 = lane & 15;
  const int m0 = blockIdx.y * 64, n0 = blockIdx.x * 128;
  // A staging: 64x32 = 256 chunks -> 1/thread
  const bf16* gA; int dstA;
  {
    int c = t;                         // 0..255
    int row = c >> 2;                  // 0..63
    int col = ((c & 3) ^ (row & 3)) * 8;
    gA = A + (size_t)(m0 + row) * KDIM + col;
    dstA = c * 8;
  }
  // B staging: 128x32 = 512 chunks -> 2/thread
  const bf16* gB[2]; int dstB[2];
  #pragma unroll
  for (int j = 0; j < 2; j++) {
    int c = t + j * 256;               // 0..511
    int row = c >> 2;                  // 0..127
    int col = ((c & 3) ^ (row & 3)) * 8;
    gB[j] = W + (size_t)(n0 + row) * KDIM + col;
    dstB[j] = c * 8;
  }
  const int swzA = quad ^ (m16 & 3);   // read-side granule
  f32x4 acc[2][4];
  #pragma unroll
  for (int i = 0; i < 2; i++)
    #pragma unroll
    for (int j = 0; j < 4; j++) acc[i][j] = (f32x4){0.f, 0.f, 0.f, 0.f};
  // prologue: stage K-tile 0 into buf 0 (A at 0, B at 2048 elems)
  async16(gA, lds + dstA);
  #pragma unroll
  for (int j = 0; j < 2; j++) async16(gB[j], lds + 2048 + dstB[j]);
  for (int kt = 0; kt < 32; ++kt) {
    __syncthreads();                   // stage(kt) arrived; buf[nxt] reads done
    const int cur = (kt & 1) * 6144;
    if (kt + 1 < 32) {
      const int nxt = 6144 - cur;
      async16(gA + (kt + 1) * 32, lds + nxt + dstA);
      #pragma unroll
      for (int j = 0; j < 2; j++) async16(gB[j] + (kt + 1) * 32, lds + nxt + 2048 + dstB[j]);
    }
    const bf16* As = lds + cur;
    const bf16* Bs = As + 2048;
    bf16x8 af[2], bfv[4];
    #pragma unroll
    for (int i = 0; i < 2; i++)
      af[i] = ld16(As + (wm * 32 + i * 16 + m16) * 32 + swzA * 8);
    #pragma unroll
    for (int i = 0; i < 4; i++)
      bfv[i] = ld16(Bs + (wn * 64 + i * 16 + m16) * 32 + swzA * 8);
    #pragma unroll
    for (int mi = 0; mi < 2; mi++)
      #pragma unroll
      for (int ni = 0; ni < 4; ni++)
        acc[mi][ni] = mfma16(af[mi], bfv[ni], acc[mi][ni]);
  }
  const int row0 = m0 + wm * 32;
  const int col0 = n0 + wn * 64;
  #pragma unroll
  for (int mi = 0; mi < 2; mi++)
    #pragma unroll
    for (int ni = 0; ni < 4; ni++)
      #pragma unroll
      for (int r = 0; r < 4; r++) {
        int row = row0 + mi * 16 + quad * 4 + r;
        int col = col0 + ni * 16 + m16;
        C[(size_t)row * 1024 + col] = (bf16)acc[mi][ni][r];
      }
}

// ---------- output projection: 128x64 tiles (512 blocks), fp32 out + bias ----------
__global__ __launch_bounds__(256, 4) void out_gemm(const bf16* __restrict__ Hm, const bf16* __restrict__ wo,
                                                const float* __restrict__ bias, float* __restrict__ out) {
  __shared__ __align__(16) bf16 lds[2 * 6144];   // 24 KB (2 bufs x (A 8KB + B 4KB))
  const int t = threadIdx.x;
  const int lane = t & 63, wave = t >> 6;
  const int wm = wave & 1, wn = wave >> 1;
  const int quad = lane >> 4, m16 = lane & 15;
  const int m0 = blockIdx.y * 128, n0 = blockIdx.x * 64;
  const bf16* gA[2]; int dstA[2];
  #pragma unroll
  for (int j = 0; j < 2; j++) {
    int c = t + j * 256;
    int row = c >> 2;
    int col = ((c & 3) ^ (row & 3)) * 8;
    gA[j] = Hm + (size_t)(m0 + row) * KDIM + col;
    dstA[j] = c * 8;
  }
  const bf16* gB; int dstB;
  {
    int c = t;                       // 0..255 (B: 64x32 = 256 chunks)
    int row = c >> 2;                // 0..63
    int col = ((c & 3) ^ (row & 3)) * 8;
    gB = wo + (size_t)(n0 + row) * KDIM + col;
    dstB = c * 8;
  }
  const int swzA = quad ^ (m16 & 3);
  f32x4 acc[4][2];
  #pragma unroll
  for (int i = 0; i < 4; i++)
    #pragma unroll
    for (int j = 0; j < 2; j++) acc[i][j] = (f32x4){0.f, 0.f, 0.f, 0.f};
  // prologue: stage K-tile 0 into buf 0
  #pragma unroll
  for (int j = 0; j < 2; j++) async16(gA[j], lds + dstA[j]);
  async16(gB, lds + 4096 + dstB);
  for (int kt = 0; kt < 32; ++kt) {
    __syncthreads();
    const int cur = (kt & 1) * 6144;
    if (kt + 1 < 32) {
      const int nxt = 6144 - cur;
      #pragma unroll
      for (int j = 0; j < 2; j++) async16(gA[j] + (kt + 1) * 32, lds + nxt + dstA[j]);
      async16(gB + (kt + 1) * 32, lds + nxt + 4096 + dstB);
    }
    const bf16* As = lds + cur;
    const bf16* Bs = As + 4096;
    bf16x8 af[4], bfv[2];
    #pragma unroll
    for (int i = 0; i < 4; i++)
      af[i] = ld16(As + (wm * 64 + i * 16 + m16) * 32 + swzA * 8);
    #pragma unroll
    for (int i = 0; i < 2; i++)
      bfv[i] = ld16(Bs + (wn * 32 + i * 16 + m16) * 32 + swzA * 8);
    #pragma unroll
    for (int mi = 0; mi < 4; mi++)
      #pragma unroll
      for (int ni = 0; ni < 2; ni++)
        acc[mi][ni] = mfma16(af[mi], bfv[ni], acc[mi][ni]);
  }
  const int row0 = m0 + wm * 64;
  const int col0 = n0 + wn * 32;
  float bv[2];
  #pragma unroll
  for (int ni = 0; ni < 2; ni++) bv[ni] = bias[col0 + ni * 16 + m16];
  #pragma unroll
  for (int mi = 0; mi < 4; mi++)
    #pragma unroll
    for (int ni = 0; ni < 2; ni++)
      #pragma unroll
      for (int r = 0; r < 4; r++) {
        int row = row0 + mi * 16 + quad * 4 + r;
        int col = col0 + ni * 16 + m16;
        out[(size_t)row * 1024 + col] = acc[mi][ni][r] + bv[ni];
      }
}

// ---------- V transpose per head-chunk: V[2048][64] -> Vt[64][2048] ----------
__global__ __launch_bounds__(256) void transpose_v(const bf16* __restrict__ V, bf16* __restrict__ Vt) {
  __shared__ bf16 T[64 * 65];
  const int t = threadIdx.x;
  const bf16* src = V + (size_t)blockIdx.y * (2048 * 64) + (size_t)blockIdx.x * 64 * 64;
  bf16* dst = Vt + (size_t)blockIdx.y * (2048 * 64) + (size_t)blockIdx.x * 64;
  #pragma unroll
  for (int j = 0; j < 2; j++) {
    int c = t + j * 256;
    int row = c >> 3, col8 = (c & 7) * 8;
    bf16x8 v = *(const bf16x8*)(src + row * 64 + col8);
    #pragma unroll
    for (int i = 0; i < 8; i++) T[row * 65 + col8 + i] = v[i];
  }
  __syncthreads();
  #pragma unroll
  for (int j = 0; j < 2; j++) {
    int c = t + j * 256;
    int d = c >> 3, k8 = (c & 7) * 8;
    bf16x8 o;
    #pragma unroll
    for (int i = 0; i < 8; i++) o[i] = T[(k8 + i) * 65 + d];
    *(bf16x8*)(dst + (size_t)d * 2048 + k8) = o;
  }
}

// ---------- flash attention: S^T/32x32 MFMA, no-max exp2 softmax, FULL-SEQ ----------
// R15 structure verbatim (best measured: 73.0-76.5us). In-block key-split (512
// threads = 8 waves; waves 0-3 keys 0..1023, waves 4-7 keys 1024..2047, same
// 128 queries). global_load_lds staging (linear LDS, XOR-pre-swizzled global
// source, XOR on read) + 64-key sub-tile double-buffer, ONE barrier per
// sub-tile. LDS 64 KB -> 2 blocks/CU (grid 512 = 2/CU is binding anyway, R19).
__global__ __launch_bounds__(512, 2) void attn_kernel(const bf16* __restrict__ Qg,
                                                      const bf16* __restrict__ Kg,
                                                      const bf16* __restrict__ Vtg,
                                                      bf16* __restrict__ Hout) {
  __shared__ __align__(16) bf16 smem[32768];  // 64 KB
  const int t = threadIdx.x;
  const int lane = t & 63;
  const int w = (t >> 6) & 3;       // wave within key-half (owns q-rows w*32..)
  const int half = t >> 8;          // 0: keys 0..1023, 1: keys 1024..2047
  const int tt = t & 255;           // staging thread id within half
  const int l31 = lane & 31, h = lane >> 5, l7 = lane & 7;
  bf16* hb = smem + half * 16384;   // this half's 32 KB (2 bufs x 16 KB)
  // XCD-pinned swizzle: L%8 = XCD (dispatch round-robin heuristic; perf-only)
  const int L = blockIdx.x + 16 * blockIdx.y;   // 0..511
  const int xcd = L & 7, j5 = L >> 3;           // j5: 0..63
  const int bh = xcd * 4 + (j5 & 3);            // 4 heads per XCD
  const int qt = j5 >> 2;                       // 0..15
  const size_t base = (size_t)bh * (2048 * 64);
  const bf16* Kp = Kg + base;
  const bf16* Vp = Vtg + base;                  // V^T rows stride 2048
  const int q = qt * 128 + w * 32 + l31;        // this lane's q-column

  // Q fragments (B-operand: n=l31, k=16kc+8h+j) in registers for the whole loop
  bf16x8 qf[4];
  #pragma unroll
  for (int kc = 0; kc < 4; kc++)
    qf[kc] = *(const bf16x8*)(Qg + base + (size_t)q * 64 + 16 * kc + 8 * h);

  f32x16 oacc[2];
  #pragma unroll
  for (int mt = 0; mt < 2; mt++)
    #pragma unroll
    for (int i = 0; i < 16; i++) oacc[mt][i] = 0.f;
  float lrow = 0.f;

  // staging geometry: per sub-tile each thread stages 2 K-chunks + 2 V-chunks
  // (16B each). LDS dst linear (c*8 elems); global source column pre-swizzled
  // by ((c&7)^(row&7))*8 so the XOR-read below lands on the right data.
  const bf16* ksrc[2]; const bf16* vsrc[2]; int dstc[2];
  #pragma unroll
  for (int j = 0; j < 2; j++) {
    int c = tt + j * 256;
    int row = c >> 3;                 // 0..63
    int sw = ((c & 7) ^ (row & 7)) * 8;
    ksrc[j] = Kp + (size_t)(half * 1024 + row) * 64 + sw;   // + st*4096 per sub-tile
    vsrc[j] = Vp + (size_t)row * 2048 + half * 1024 + sw;   // + st*64 per sub-tile
    dstc[j] = c * 8;
  }

  // prologue: stage sub-tile 0 into buf 0
  #pragma unroll
  for (int j = 0; j < 2; j++) {
    async16(ksrc[j], hb + dstc[j]);
    async16(vsrc[j], hb + 4096 + dstc[j]);
  }

  for (int st = 0; st < 16; ++st) {
    __syncthreads();   // stage(st) arrived (vmcnt drained) AND buf[(st+1)&1] free
    const int buf = st & 1;
    if (st + 1 < 16) {
      const int nb = (buf ^ 1) * 8192;
      #pragma unroll
      for (int j = 0; j < 2; j++) {
        async16(ksrc[j] + (st + 1) * 4096, hb + nb + dstc[j]);
        async16(vsrc[j] + (st + 1) * 64,   hb + nb + 4096 + dstc[j]);
      }
    }
    bf16* Kb = hb + buf * 8192;
    bf16* Vb = Kb + 4096;

    // two 32-key groups per 64-key sub-tile
    #pragma unroll
    for (int mtq = 0; mtq < 2; mtq++) {
      f32x16 sacc;
      #pragma unroll
      for (int i = 0; i < 16; i++) sacc[i] = 0.f;
      #pragma unroll
      for (int kc = 0; kc < 4; kc++) {
        bf16x8 kf = ld16(Kb + (32 * mtq + l31) * 64 + (((2 * kc + h) ^ l7) << 3));
        sacc = mfma32(kf, qf[kc], sacc);
      }
      int pd[8];
      float sum = 0.f;
      #pragma unroll
      for (int p = 0; p < 8; p++) {
        float p0 = fast_exp2(sacc[2 * p]);
        float p1 = fast_exp2(sacc[2 * p + 1]);
        sum += p0 + p1;
        pd[p] = packbf2(p0, p1);
      }
      lrow += sum;
      // O^T += V^T . P^T for this group's two 16-key chunks
      #pragma unroll
      for (int c1 = 0; c1 < 2; c1++) {
        const int kcp = 2 * mtq + c1;
        const int rro = 2 * c1 + h;        // own reg-group
        const int rrp = 2 * c1 + 1 - h;    // what the partner half needs from us
        int s0 = __shfl_xor(pd[2 * rrp], 32, 64);
        int s1 = __shfl_xor(pd[2 * rrp + 1], 32, 64);
        int o0 = pd[2 * rro], o1 = pd[2 * rro + 1];
        i32x4 w4;
        w4.x = h ? s0 : o0;
        w4.y = h ? s1 : o1;
        w4.z = h ? o0 : s0;
        w4.w = h ? o1 : s1;
        bf16x8 pfrag = __builtin_bit_cast(bf16x8, w4);
        #pragma unroll
        for (int mtd = 0; mtd < 2; mtd++) {
          bf16x8 vf = ld16(Vb + (32 * mtd + l31) * 64 + (((2 * kcp + h) ^ l7) << 3));
          oacc[mtd] = mfma32(vf, pfrag, oacc[mtd]);
        }
      }
    }
  }
  __syncthreads();   // all LDS reads done before epilogue reuses smem

  // epilogue: in-block merge of the two key-halves, normalize, transpose
  // O^T -> O[q][d] through LDS, store bf16 H. Wave-pair (w, half=0/1) shares an
  // 8 KB fp32 region: half1 deposits unnormalized O^T + l, half0 adds its own,
  // normalizes, writes back; then all 8 waves cooperatively store bf16.
  lrow += __shfl_xor(lrow, 32, 64);
  float* Sf = (float*)smem;
  float* Tf = Sf + w * 2048;        // [64 d][32 q] per wave-pair
  float* Lb = Sf + 8192 + w * 32;   // l partials, one row per wave-pair
  if (half) {
    #pragma unroll
    for (int mt = 0; mt < 2; mt++)
      #pragma unroll
      for (int r = 0; r < 16; r++) {
        int d = 32 * mt + (r & 3) + 8 * (r >> 2) + 4 * h;
        Tf[d * 32 + l31] = oacc[mt][r];
      }
    if (!h) Lb[l31] = lrow;
  }
  __syncthreads();
  if (!half) {
    float linv = 1.f / (lrow + Lb[l31]);
    #pragma unroll
    for (int mt = 0; mt < 2; mt++)
      #pragma unroll
      for (int r = 0; r < 16; r++) {
        int d = 32 * mt + (r & 3) + 8 * (r >> 2) + 4 * h;
        Tf[d * 32 + l31] = (oacc[mt][r] + Tf[d * 32 + l31]) * linv;
      }
  }
  __syncthreads();
  bf16* Hq = Hout + base + (size_t)(qt * 128 + w * 32 + l31) * 64 + 32 * h;
  #pragma unroll
  for (int s = 0; s < 2; s++) {
    int se = half * 2 + s;           // each half stores 2 of the 4 d-octets
    bf16x8 o;
    #pragma unroll
    for (int i = 0; i < 8; i++) o[i] = (bf16)Tf[(32 * h + se * 8 + i) * 32 + l31];
    *(bf16x8*)(Hq + se * 8) = o;
  }
}

// ---------- launch ----------
extern "C" void kernel_launch(void* const* d_in, const int* in_sizes, int n_in,
                              void* d_out, int out_size, void* d_ws, size_t ws_size,
                              hipStream_t stream) {
  const float* Xq = (const float*)d_in[0];
  const float* Xk = (const float*)d_in[1];
  const float* Xv = (const float*)d_in[2];
  const float* Wq = (const float*)d_in[3];
  const float* Wk = (const float*)d_in[4];
  const float* Wv = (const float*)d_in[5];
  const float* Wo = (const float*)d_in[6];
  const float* bo = (const float*)d_in[7];

  bf16* ws = (bf16*)d_ws;
  bf16* xq = ws;                 // casts write [xq xk xv wq wk wv wo] contiguously
  bf16* xk = ws + XSZ;
  bf16* xv = ws + 2 * (size_t)XSZ;
  bf16* wq = ws + 3 * (size_t)XSZ;
  bf16* wk = wq + WSZ;
  bf16* wv = wk + WSZ;
  bf16* wo = wv + WSZ;
  bf16* q  = wo + WSZ;
  bf16* k  = q + XSZ;
  bf16* v  = k + XSZ;
  bf16* vt = xv;                 // alias: X_v dead after projection
  bf16* h  = xq;                 // alias: X_q dead after projection

  cast_all<<<8192, 256, 0, stream>>>(Xq, Xk, Xv, Wq, Wk, Wv, Wo, ws);
  proj_gemm<<<dim3(8, 64, 3), 256, 0, stream>>>(xq, xk, xv, wq, wk, wv, q, k, v);
  transpose_v<<<dim3(32, 32), 256, 0, stream>>>(v, vt);
  attn_kernel<<<dim3(16, 32), 512, 0, stream>>>(q, k, vt, h);
  out_gemm<<<dim3(16, 32), 256, 0, stream>>>(h, wo, bo, (float*)d_out);
}

// Round 13
// 232.471 us; speedup vs baseline: 1.0490x; 1.0490x over previous
//
#include <hip/hip_runtime.h>

typedef __bf16 bf16;
typedef bf16 bf16x8 __attribute__((ext_vector_type(8)));
typedef bf16 bf16x4 __attribute__((ext_vector_type(4)));
typedef bf16 bf16x2 __attribute__((ext_vector_type(2)));
typedef float f32x4 __attribute__((ext_vector_type(4)));
typedef float f32x16 __attribute__((ext_vector_type(16)));
typedef int i32x4 __attribute__((ext_vector_type(4)));

#define XSZ 4194304   // 4096*1024 elements (B*S x D)
#define WSZ 1048576   // 1024*1024
#define KDIM 1024
// 0.125 * log2(e): fold 1/sqrt(dk) AND the exp->exp2 conversion into W_q
#define QSCALE 0.1803368801111137f

// ---------- helpers ----------
__device__ __forceinline__ void async16(const bf16* g, bf16* l) {
  __builtin_amdgcn_global_load_lds(
      (const __attribute__((address_space(1))) unsigned int*)g,
      (__attribute__((address_space(3))) unsigned int*)l, 16, 0, 0);
}

__device__ __forceinline__ bf16x8 ld16(const bf16* p) {  // one ds_read_b128 (16B-aligned)
  return __builtin_bit_cast(bf16x8, *(const i32x4*)p);
}

__device__ __forceinline__ f32x4 mfma16(bf16x8 a, bf16x8 b, f32x4 c) {
  return __builtin_amdgcn_mfma_f32_16x16x32_bf16(a, b, c, 0, 0, 0);
}
__device__ __forceinline__ f32x16 mfma32(bf16x8 a, bf16x8 b, f32x16 c) {
  return __builtin_amdgcn_mfma_f32_32x32x16_bf16(a, b, c, 0, 0, 0);
}

__device__ __forceinline__ int packbf2(float lo, float hi) {
  bf16x2 t; t[0] = (bf16)lo; t[1] = (bf16)hi;
  return __builtin_bit_cast(int, t);
}

// exp2f without fast-math lowers to the accurate OCML software routine (~25 VALU
// instr). v_exp_f32 is 1-ulp, plenty for bf16.
__device__ __forceinline__ float fast_exp2(float x) {
#if __has_builtin(__builtin_amdgcn_exp2f)
  return __builtin_amdgcn_exp2f(x);
#else
  return exp2f(x);
#endif
}

// ======================= SESSION LEDGER (R9-R22) =======================
// R10: permlane32_swap half-broadcast misrouted data (absmax 0.19) — keep the
//      proven shfl_xor+cndmask P-exchange.
// R11: __launch_bounds__ 2nd arg = BLOCKS/CU on this toolchain; VGPR cap =
//      2048/(blocks*waves). (512,4) -> cap 64 -> spills (500 MB scratch).
// R12: in-block key-split (8 waves, 2 key-halves, LDS merge): attn 104->82us.
// R13: attn s_setprio REGRESSED (sched fence, -24 VGPR); GEMM BK64+XOR swz ok.
// R15: attn staging -> global_load_lds + both-sides XOR swizzle + 64-key
//      subtile dbuf, one barrier/subtile: attn 73-76us, VGPR 60. BEST attn.
// R16: proj/out GEMM -> BK=32 2-phase dbuf (one barrier/K-tile, latency
//      hidden): best total family 230.8-232.5us.
// R17: padded reg-staged attn killed ALL bank conflicts (4.19M->0) yet
//      REGRESSED 73->85us: conflicts were not critical-path. Counter size
//      != bottleneck.
// R18: proj/out (256,4): neutral. Kept.
// R19: 32-key subtiles REGRESSED 73->93us: attn occupancy is GRID-limited
//      (512 blocks = 2/CU exactly). occupancy = min(grid/CU, LDS, VGPR) —
//      check grid FIRST.
// R21: proj 64x128 tile (1536 blocks, 5/CU) REGRESSED ~8us: proj not
//      wave-starved; extra B-panel traffic. REVERTED (R22 = R18 exact).
// Remaining theorized levers (4-way key-split attn @1024 blocks; 8-phase
// 256^2 GEMM) are multi-part rebuilds with negative EV at the measured
// noise floor (+-5-10us) and observed correctness-failure rate.
// =======================================================================

// ---------- fused fp32 -> bf16 cast for all 7 tensors (dsts contiguous in ws) ----------
__global__ __launch_bounds__(256) void cast_all(const float* __restrict__ Xq, const float* __restrict__ Xk,
                                                const float* __restrict__ Xv, const float* __restrict__ Wq,
                                                const float* __restrict__ Wk, const float* __restrict__ Wv,
                                                const float* __restrict__ Wo, bf16* __restrict__ dst) {
  size_t i = ((size_t)blockIdx.x * 256 + threadIdx.x) * 8;
  const float* src; size_t off; float scale = 1.0f;
  if (i < XSZ)                { src = Xq; off = i; }
  else if (i < 2 * (size_t)XSZ) { src = Xk; off = i - XSZ; }
  else if (i < 3 * (size_t)XSZ) { src = Xv; off = i - 2 * (size_t)XSZ; }
  else if (i < 3 * (size_t)XSZ + WSZ) { src = Wq; off = i - 3 * (size_t)XSZ; scale = QSCALE; }
  else if (i < 3 * (size_t)XSZ + 2 * (size_t)WSZ) { src = Wk; off = i - 3 * (size_t)XSZ - WSZ; }
  else if (i < 3 * (size_t)XSZ + 3 * (size_t)WSZ) { src = Wv; off = i - 3 * (size_t)XSZ - 2 * (size_t)WSZ; }
  else                        { src = Wo; off = i - 3 * (size_t)XSZ - 3 * (size_t)WSZ; }
  float4 a = *(const float4*)(src + off);
  float4 b = *(const float4*)(src + off + 4);
  bf16x8 o;
  o[0] = (bf16)(a.x * scale); o[1] = (bf16)(a.y * scale);
  o[2] = (bf16)(a.z * scale); o[3] = (bf16)(a.w * scale);
  o[4] = (bf16)(b.x * scale); o[5] = (bf16)(b.y * scale);
  o[6] = (bf16)(b.z * scale); o[7] = (bf16)(b.w * scale);
  *(bf16x8*)(dst + i) = o;
}

// ---------- NT GEMM core, BK=32 2-phase dbuf: C[128x128] += A[m,:] . B[n,:] ----------
__device__ __forceinline__ void gemm_nt_core(const bf16* __restrict__ A, const bf16* __restrict__ Bm,
                                             int m0, int n0, bf16* lds, f32x4 acc[4][4]) {
  const int t = threadIdx.x;
  const int lane = t & 63, wave = t >> 6;
  const int wm = wave & 1, wn = wave >> 1;
  const int quad = lane >> 4, m16 = lane & 15;
  const bf16* gA[2]; int dstc[2];
  #pragma unroll
  for (int j = 0; j < 2; j++) {
    int c = t + j * 256;               // 0..511
    int row = c >> 2;                  // 0..127
    int col = ((c & 3) ^ (row & 3)) * 8;
    gA[j] = A + (size_t)(m0 + row) * KDIM + col;
    dstc[j] = c * 8;
  }
  const ptrdiff_t dBA = (Bm + (size_t)n0 * KDIM) - (A + (size_t)m0 * KDIM);
  const int swzA = quad ^ (m16 & 3);   // read-side granule
  // prologue: stage K-tile 0 into buf 0
  #pragma unroll
  for (int j = 0; j < 2; j++) {
    async16(gA[j], lds + dstc[j]);
    async16(gA[j] + dBA, lds + 4096 + dstc[j]);
  }
  for (int kt = 0; kt < 32; ++kt) {
    __syncthreads();                   // stage(kt) arrived; buf[nxt] reads done
    const int cur = (kt & 1) * 8192;
    if (kt + 1 < 32) {
      const int nxt = 8192 - cur;
      #pragma unroll
      for (int j = 0; j < 2; j++) {
        async16(gA[j] + (kt + 1) * 32, lds + nxt + dstc[j]);
        async16(gA[j] + dBA + (kt + 1) * 32, lds + nxt + 4096 + dstc[j]);
      }
    }
    const bf16* As = lds + cur;
    const bf16* Bs = As + 4096;
    bf16x8 af[4], bfv[4];
    #pragma unroll
    for (int i = 0; i < 4; i++)
      af[i] = ld16(As + (wm * 64 + i * 16 + m16) * 32 + swzA * 8);
    #pragma unroll
    for (int i = 0; i < 4; i++)
      bfv[i] = ld16(Bs + (wn * 64 + i * 16 + m16) * 32 + swzA * 8);
    #pragma unroll
    for (int mi = 0; mi < 4; mi++)
      #pragma unroll
      for (int ni = 0; ni < 4; ni++)
        acc[mi][ni] = mfma16(af[mi], bfv[ni], acc[mi][ni]);
  }
}

// ---------- fused Q/K/V projection ----------
__global__ __launch_bounds__(256, 4) void proj_gemm(const bf16* __restrict__ xq, const bf16* __restrict__ xk,
                                                 const bf16* __restrict__ xv, const bf16* __restrict__ wq,
                                                 const bf16* __restrict__ wk, const bf16* __restrict__ wv,
                                                 bf16* __restrict__ Qo, bf16* __restrict__ Ko,
                                                 bf16* __restrict__ Vo) {
  __shared__ __align__(16) bf16 lds[2 * 8192];   // 32 KB (2 bufs x (A+B))
  const int z = blockIdx.z;
  const bf16* A = (z == 0) ? xq : (z == 1) ? xk : xv;
  const bf16* W = (z == 0) ? wq : (z == 1) ? wk : wv;
  bf16* C = (z == 0) ? Qo : (z == 1) ? Ko : Vo;
  f32x4 acc[4][4];
  #pragma unroll
  for (int i = 0; i < 4; i++)
    #pragma unroll
    for (int j = 0; j < 4; j++) acc[i][j] = (f32x4){0.f, 0.f, 0.f, 0.f};
  gemm_nt_core(A, W, blockIdx.y * 128, blockIdx.x * 128, lds, acc);
  const int lane = threadIdx.x & 63, wave = threadIdx.x >> 6;
  const int wm = wave & 1, wn = wave >> 1, quad = lane >> 4, m16 = lane & 15;
  const int row0 = blockIdx.y * 128 + wm * 64;
  const int col0 = blockIdx.x * 128 + wn * 64;
  #pragma unroll
  for (int mi = 0; mi < 4; mi++)
    #pragma unroll
    for (int ni = 0; ni < 4; ni++)
      #pragma unroll
      for (int r = 0; r < 4; r++) {
        int row = row0 + mi * 16 + quad * 4 + r;
        int col = col0 + ni * 16 + m16;
        C[(size_t)row * 1024 + col] = (bf16)acc[mi][ni][r];
      }
}

// ---------- output projection: 128x64 tiles (512 blocks), fp32 out + bias ----------
__global__ __launch_bounds__(256, 4) void out_gemm(const bf16* __restrict__ Hm, const bf16* __restrict__ wo,
                                                const float* __restrict__ bias, float* __restrict__ out) {
  __shared__ __align__(16) bf16 lds[2 * 6144];   // 24 KB (2 bufs x (A 8KB + B 4KB))
  const int t = threadIdx.x;
  const int lane = t & 63, wave = t >> 6;
  const int wm = wave & 1, wn = wave >> 1;
  const int quad = lane >> 4, m16 = lane & 15;
  const int m0 = blockIdx.y * 128, n0 = blockIdx.x * 64;
  const bf16* gA[2]; int dstA[2];
  #pragma unroll
  for (int j = 0; j < 2; j++) {
    int c = t + j * 256;
    int row = c >> 2;
    int col = ((c & 3) ^ (row & 3)) * 8;
    gA[j] = Hm + (size_t)(m0 + row) * KDIM + col;
    dstA[j] = c * 8;
  }
  const bf16* gB; int dstB;
  {
    int c = t;                       // 0..255 (B: 64x32 = 256 chunks)
    int row = c >> 2;                // 0..63
    int col = ((c & 3) ^ (row & 3)) * 8;
    gB = wo + (size_t)(n0 + row) * KDIM + col;
    dstB = c * 8;
  }
  const int swzA = quad ^ (m16 & 3);
  f32x4 acc[4][2];
  #pragma unroll
  for (int i = 0; i < 4; i++)
    #pragma unroll
    for (int j = 0; j < 2; j++) acc[i][j] = (f32x4){0.f, 0.f, 0.f, 0.f};
  // prologue: stage K-tile 0 into buf 0
  #pragma unroll
  for (int j = 0; j < 2; j++) async16(gA[j], lds + dstA[j]);
  async16(gB, lds + 4096 + dstB);
  for (int kt = 0; kt < 32; ++kt) {
    __syncthreads();
    const int cur = (kt & 1) * 6144;
    if (kt + 1 < 32) {
      const int nxt = 6144 - cur;
      #pragma unroll
      for (int j = 0; j < 2; j++) async16(gA[j] + (kt + 1) * 32, lds + nxt + dstA[j]);
      async16(gB + (kt + 1) * 32, lds + nxt + 4096 + dstB);
    }
    const bf16* As = lds + cur;
    const bf16* Bs = As + 4096;
    bf16x8 af[4], bfv[2];
    #pragma unroll
    for (int i = 0; i < 4; i++)
      af[i] = ld16(As + (wm * 64 + i * 16 + m16) * 32 + swzA * 8);
    #pragma unroll
    for (int i = 0; i < 2; i++)
      bfv[i] = ld16(Bs + (wn * 32 + i * 16 + m16) * 32 + swzA * 8);
    #pragma unroll
    for (int mi = 0; mi < 4; mi++)
      #pragma unroll
      for (int ni = 0; ni < 2; ni++)
        acc[mi][ni] = mfma16(af[mi], bfv[ni], acc[mi][ni]);
  }
  const int row0 = m0 + wm * 64;
  const int col0 = n0 + wn * 32;
  float bv[2];
  #pragma unroll
  for (int ni = 0; ni < 2; ni++) bv[ni] = bias[col0 + ni * 16 + m16];
  #pragma unroll
  for (int mi = 0; mi < 4; mi++)
    #pragma unroll
    for (int ni = 0; ni < 2; ni++)
      #pragma unroll
      for (int r = 0; r < 4; r++) {
        int row = row0 + mi * 16 + quad * 4 + r;
        int col = col0 + ni * 16 + m16;
        out[(size_t)row * 1024 + col] = acc[mi][ni][r] + bv[ni];
      }
}

// ---------- V transpose per head-chunk: V[2048][64] -> Vt[64][2048] ----------
__global__ __launch_bounds__(256) void transpose_v(const bf16* __restrict__ V, bf16* __restrict__ Vt) {
  __shared__ bf16 T[64 * 65];
  const int t = threadIdx.x;
  const bf16* src = V + (size_t)blockIdx.y * (2048 * 64) + (size_t)blockIdx.x * 64 * 64;
  bf16* dst = Vt + (size_t)blockIdx.y * (2048 * 64) + (size_t)blockIdx.x * 64;
  #pragma unroll
  for (int j = 0; j < 2; j++) {
    int c = t + j * 256;
    int row = c >> 3, col8 = (c & 7) * 8;
    bf16x8 v = *(const bf16x8*)(src + row * 64 + col8);
    #pragma unroll
    for (int i = 0; i < 8; i++) T[row * 65 + col8 + i] = v[i];
  }
  __syncthreads();
  #pragma unroll
  for (int j = 0; j < 2; j++) {
    int c = t + j * 256;
    int d = c >> 3, k8 = (c & 7) * 8;
    bf16x8 o;
    #pragma unroll
    for (int i = 0; i < 8; i++) o[i] = T[(k8 + i) * 65 + d];
    *(bf16x8*)(dst + (size_t)d * 2048 + k8) = o;
  }
}

// ---------- flash attention: S^T/32x32 MFMA, no-max exp2 softmax, FULL-SEQ ----------
// R15 structure verbatim (best measured: 73.0-76.5us). In-block key-split (512
// threads = 8 waves; waves 0-3 keys 0..1023, waves 4-7 keys 1024..2047, same
// 128 queries). global_load_lds staging (linear LDS, XOR-pre-swizzled global
// source, XOR on read) + 64-key sub-tile double-buffer, ONE barrier per
// sub-tile. LDS 64 KB -> 2 blocks/CU (grid 512 = 2/CU is binding anyway, R19).
__global__ __launch_bounds__(512, 2) void attn_kernel(const bf16* __restrict__ Qg,
                                                      const bf16* __restrict__ Kg,
                                                      const bf16* __restrict__ Vtg,
                                                      bf16* __restrict__ Hout) {
  __shared__ __align__(16) bf16 smem[32768];  // 64 KB
  const int t = threadIdx.x;
  const int lane = t & 63;
  const int w = (t >> 6) & 3;       // wave within key-half (owns q-rows w*32..)
  const int half = t >> 8;          // 0: keys 0..1023, 1: keys 1024..2047
  const int tt = t & 255;           // staging thread id within half
  const int l31 = lane & 31, h = lane >> 5, l7 = lane & 7;
  bf16* hb = smem + half * 16384;   // this half's 32 KB (2 bufs x 16 KB)
  // XCD-pinned swizzle: L%8 = XCD (dispatch round-robin heuristic; perf-only)
  const int L = blockIdx.x + 16 * blockIdx.y;   // 0..511
  const int xcd = L & 7, j5 = L >> 3;           // j5: 0..63
  const int bh = xcd * 4 + (j5 & 3);            // 4 heads per XCD
  const int qt = j5 >> 2;                       // 0..15
  const size_t base = (size_t)bh * (2048 * 64);
  const bf16* Kp = Kg + base;
  const bf16* Vp = Vtg + base;                  // V^T rows stride 2048
  const int q = qt * 128 + w * 32 + l31;        // this lane's q-column

  // Q fragments (B-operand: n=l31, k=16kc+8h+j) in registers for the whole loop
  bf16x8 qf[4];
  #pragma unroll
  for (int kc = 0; kc < 4; kc++)
    qf[kc] = *(const bf16x8*)(Qg + base + (size_t)q * 64 + 16 * kc + 8 * h);

  f32x16 oacc[2];
  #pragma unroll
  for (int mt = 0; mt < 2; mt++)
    #pragma unroll
    for (int i = 0; i < 16; i++) oacc[mt][i] = 0.f;
  float lrow = 0.f;

  // staging geometry: per sub-tile each thread stages 2 K-chunks + 2 V-chunks
  // (16B each). LDS dst linear (c*8 elems); global source column pre-swizzled
  // by ((c&7)^(row&7))*8 so the XOR-read below lands on the right data.
  const bf16* ksrc[2]; const bf16* vsrc[2]; int dstc[2];
  #pragma unroll
  for (int j = 0; j < 2; j++) {
    int c = tt + j * 256;
    int row = c >> 3;                 // 0..63
    int sw = ((c & 7) ^ (row & 7)) * 8;
    ksrc[j] = Kp + (size_t)(half * 1024 + row) * 64 + sw;   // + st*4096 per sub-tile
    vsrc[j] = Vp + (size_t)row * 2048 + half * 1024 + sw;   // + st*64 per sub-tile
    dstc[j] = c * 8;
  }

  // prologue: stage sub-tile 0 into buf 0
  #pragma unroll
  for (int j = 0; j < 2; j++) {
    async16(ksrc[j], hb + dstc[j]);
    async16(vsrc[j], hb + 4096 + dstc[j]);
  }

  for (int st = 0; st < 16; ++st) {
    __syncthreads();   // stage(st) arrived (vmcnt drained) AND buf[(st+1)&1] free
    const int buf = st & 1;
    if (st + 1 < 16) {
      const int nb = (buf ^ 1) * 8192;
      #pragma unroll
      for (int j = 0; j < 2; j++) {
        async16(ksrc[j] + (st + 1) * 4096, hb + nb + dstc[j]);
        async16(vsrc[j] + (st + 1) * 64,   hb + nb + 4096 + dstc[j]);
      }
    }
    bf16* Kb = hb + buf * 8192;
    bf16* Vb = Kb + 4096;

    // two 32-key groups per 64-key sub-tile
    #pragma unroll
    for (int mtq = 0; mtq < 2; mtq++) {
      f32x16 sacc;
      #pragma unroll
      for (int i = 0; i < 16; i++) sacc[i] = 0.f;
      #pragma unroll
      for (int kc = 0; kc < 4; kc++) {
        bf16x8 kf = ld16(Kb + (32 * mtq + l31) * 64 + (((2 * kc + h) ^ l7) << 3));
        sacc = mfma32(kf, qf[kc], sacc);
      }
      int pd[8];
      float sum = 0.f;
      #pragma unroll
      for (int p = 0; p < 8; p++) {
        float p0 = fast_exp2(sacc[2 * p]);
        float p1 = fast_exp2(sacc[2 * p + 1]);
        sum += p0 + p1;
        pd[p] = packbf2(p0, p1);
      }
      lrow += sum;
      // O^T += V^T . P^T for this group's two 16-key chunks
      #pragma unroll
      for (int c1 = 0; c1 < 2; c1++) {
        const int kcp = 2 * mtq + c1;
        const int rro = 2 * c1 + h;        // own reg-group
        const int rrp = 2 * c1 + 1 - h;    // what the partner half needs from us
        int s0 = __shfl_xor(pd[2 * rrp], 32, 64);
        int s1 = __shfl_xor(pd[2 * rrp + 1], 32, 64);
        int o0 = pd[2 * rro], o1 = pd[2 * rro + 1];
        i32x4 w4;
        w4.x = h ? s0 : o0;
        w4.y = h ? s1 : o1;
        w4.z = h ? o0 : s0;
        w4.w = h ? o1 : s1;
        bf16x8 pfrag = __builtin_bit_cast(bf16x8, w4);
        #pragma unroll
        for (int mtd = 0; mtd < 2; mtd++) {
          bf16x8 vf = ld16(Vb + (32 * mtd + l31) * 64 + (((2 * kcp + h) ^ l7) << 3));
          oacc[mtd] = mfma32(vf, pfrag, oacc[mtd]);
        }
      }
    }
  }
  __syncthreads();   // all LDS reads done before epilogue reuses smem

  // epilogue: in-block merge of the two key-halves, normalize, transpose
  // O^T -> O[q][d] through LDS, store bf16 H. Wave-pair (w, half=0/1) shares an
  // 8 KB fp32 region: half1 deposits unnormalized O^T + l, half0 adds its own,
  // normalizes, writes back; then all 8 waves cooperatively store bf16.
  lrow += __shfl_xor(lrow, 32, 64);
  float* Sf = (float*)smem;
  float* Tf = Sf + w * 2048;        // [64 d][32 q] per wave-pair
  float* Lb = Sf + 8192 + w * 32;   // l partials, one row per wave-pair
  if (half) {
    #pragma unroll
    for (int mt = 0; mt < 2; mt++)
      #pragma unroll
      for (int r = 0; r < 16; r++) {
        int d = 32 * mt + (r & 3) + 8 * (r >> 2) + 4 * h;
        Tf[d * 32 + l31] = oacc[mt][r];
      }
    if (!h) Lb[l31] = lrow;
  }
  __syncthreads();
  if (!half) {
    float linv = 1.f / (lrow + Lb[l31]);
    #pragma unroll
    for (int mt = 0; mt < 2; mt++)
      #pragma unroll
      for (int r = 0; r < 16; r++) {
        int d = 32 * mt + (r & 3) + 8 * (r >> 2) + 4 * h;
        Tf[d * 32 + l31] = (oacc[mt][r] + Tf[d * 32 + l31]) * linv;
      }
  }
  __syncthreads();
  bf16* Hq = Hout + base + (size_t)(qt * 128 + w * 32 + l31) * 64 + 32 * h;
  #pragma unroll
  for (int s = 0; s < 2; s++) {
    int se = half * 2 + s;           // each half stores 2 of the 4 d-octets
    bf16x8 o;
    #pragma unroll
    for (int i = 0; i < 8; i++) o[i] = (bf16)Tf[(32 * h + se * 8 + i) * 32 + l31];
    *(bf16x8*)(Hq + se * 8) = o;
  }
}

// ---------- launch ----------
extern "C" void kernel_launch(void* const* d_in, const int* in_sizes, int n_in,
                              void* d_out, int out_size, void* d_ws, size_t ws_size,
                              hipStream_t stream) {
  const float* Xq = (const float*)d_in[0];
  const float* Xk = (const float*)d_in[1];
  const float* Xv = (const float*)d_in[2];
  const float* Wq = (const float*)d_in[3];
  const float* Wk = (const float*)d_in[4];
  const float* Wv = (const float*)d_in[5];
  const float* Wo = (const float*)d_in[6];
  const float* bo = (const float*)d_in[7];

  bf16* ws = (bf16*)d_ws;
  bf16* xq = ws;                 // casts write [xq xk xv wq wk wv wo] contiguously
  bf16* xk = ws + XSZ;
  bf16* xv = ws + 2 * (size_t)XSZ;
  bf16* wq = ws + 3 * (size_t)XSZ;
  bf16* wk = wq + WSZ;
  bf16* wv = wk + WSZ;
  bf16* wo = wv + WSZ;
  bf16* q  = wo + WSZ;
  bf16* k  = q + XSZ;
  bf16* v  = k + XSZ;
  bf16* vt = xv;                 // alias: X_v dead after projection
  bf16* h  = xq;                 // alias: X_q dead after projection

  cast_all<<<8192, 256, 0, stream>>>(Xq, Xk, Xv, Wq, Wk, Wv, Wo, ws);
  proj_gemm<<<dim3(8, 32, 3), 256, 0, stream>>>(xq, xk, xv, wq, wk, wv, q, k, v);
  transpose_v<<<dim3(32, 32), 256, 0, stream>>>(v, vt);
  attn_kernel<<<dim3(16, 32), 512, 0, stream>>>(q, k, vt, h);
  out_gemm<<<dim3(16, 32), 256, 0, stream>>>(h, wo, bo, (float*)d_out);
}

// Round 14
// 230.725 us; speedup vs baseline: 1.0570x; 1.0076x over previous
//
#include <hip/hip_runtime.h>

typedef __bf16 bf16;
typedef bf16 bf16x8 __attribute__((ext_vector_type(8)));
typedef bf16 bf16x4 __attribute__((ext_vector_type(4)));
typedef bf16 bf16x2 __attribute__((ext_vector_type(2)));
typedef float f32x4 __attribute__((ext_vector_type(4)));
typedef float f32x16 __attribute__((ext_vector_type(16)));
typedef int i32x4 __attribute__((ext_vector_type(4)));

#define XSZ 4194304   // 4096*1024 elements (B*S x D)
#define WSZ 1048576   // 1024*1024
#define KDIM 1024
// 0.125 * log2(e): fold 1/sqrt(dk) AND the exp->exp2 conversion into W_q
#define QSCALE 0.1803368801111137f

// ---------- helpers ----------
__device__ __forceinline__ void async16(const bf16* g, bf16* l) {
  __builtin_amdgcn_global_load_lds(
      (const __attribute__((address_space(1))) unsigned int*)g,
      (__attribute__((address_space(3))) unsigned int*)l, 16, 0, 0);
}

__device__ __forceinline__ bf16x8 ld16(const bf16* p) {  // one ds_read_b128 (16B-aligned)
  return __builtin_bit_cast(bf16x8, *(const i32x4*)p);
}

__device__ __forceinline__ f32x4 mfma16(bf16x8 a, bf16x8 b, f32x4 c) {
  return __builtin_amdgcn_mfma_f32_16x16x32_bf16(a, b, c, 0, 0, 0);
}
__device__ __forceinline__ f32x16 mfma32(bf16x8 a, bf16x8 b, f32x16 c) {
  return __builtin_amdgcn_mfma_f32_32x32x16_bf16(a, b, c, 0, 0, 0);
}

__device__ __forceinline__ int packbf2(float lo, float hi) {
  bf16x2 t; t[0] = (bf16)lo; t[1] = (bf16)hi;
  return __builtin_bit_cast(int, t);
}

// exp2f without fast-math lowers to the accurate OCML software routine (~25 VALU
// instr). v_exp_f32 is 1-ulp, plenty for bf16.
__device__ __forceinline__ float fast_exp2(float x) {
#if __has_builtin(__builtin_amdgcn_exp2f)
  return __builtin_amdgcn_exp2f(x);
#else
  return exp2f(x);
#endif
}

// ======================= SESSION LEDGER (R9-R23) =======================
// R10: permlane32_swap half-broadcast misrouted data (absmax 0.19) — keep the
//      proven shfl_xor+cndmask P-exchange.
// R11: __launch_bounds__ 2nd arg = BLOCKS/CU on this toolchain; VGPR cap =
//      2048/(blocks*waves). (512,4) -> cap 64 -> spills (500 MB scratch).
// R12: in-block key-split (8 waves, 2 key-halves, LDS merge): attn 104->82us.
//      Occupancy 2->4 waves/SIMD on a latency-bound MFMA loop = -25%.
// R13: attn s_setprio REGRESSED (sched fence); GEMM BK64+XOR swz ok.
// R15: attn staging -> global_load_lds + both-sides XOR swizzle + 64-key
//      subtile dbuf, one barrier/subtile: attn 73-76us, VGPR 60. BEST attn.
// R16: proj/out GEMM -> BK=32 2-phase dbuf: best total family 230.8-232.5us.
// R17: padded reg-staged attn killed ALL bank conflicts yet REGRESSED:
//      conflicts were not critical-path. Counter size != bottleneck.
// R19: 32-key subtiles REGRESSED: attn occupancy is GRID-limited (512 blocks
//      = 2/CU). occupancy = min(grid/CU, LDS, VGPR) — check grid FIRST.
// R21: proj 64x128 tile REGRESSED: halving M-tile DOUBLED B-panel traffic.
//      Tile shrink is only free when panel traffic is unchanged.
// R23: out_gemm 128x64 -> 64x64 (grid 512->1024 = 2->4 blocks/CU = 4 waves/
//      SIMD). Traffic-neutral by arithmetic (A 128MB, B 64MB either way) —
//      the R21 flaw does not apply. Same BK=32 2-phase core, same K-order ->
//      bit-identical. R12 precedent: latency-bound MFMA at 2->4 waves/SIMD.
// =======================================================================

// ---------- fused fp32 -> bf16 cast for all 7 tensors (dsts contiguous in ws) ----------
__global__ __launch_bounds__(256) void cast_all(const float* __restrict__ Xq, const float* __restrict__ Xk,
                                                const float* __restrict__ Xv, const float* __restrict__ Wq,
                                                const float* __restrict__ Wk, const float* __restrict__ Wv,
                                                const float* __restrict__ Wo, bf16* __restrict__ dst) {
  size_t i = ((size_t)blockIdx.x * 256 + threadIdx.x) * 8;
  const float* src; size_t off; float scale = 1.0f;
  if (i < XSZ)                { src = Xq; off = i; }
  else if (i < 2 * (size_t)XSZ) { src = Xk; off = i - XSZ; }
  else if (i < 3 * (size_t)XSZ) { src = Xv; off = i - 2 * (size_t)XSZ; }
  else if (i < 3 * (size_t)XSZ + WSZ) { src = Wq; off = i - 3 * (size_t)XSZ; scale = QSCALE; }
  else if (i < 3 * (size_t)XSZ + 2 * (size_t)WSZ) { src = Wk; off = i - 3 * (size_t)XSZ - WSZ; }
  else if (i < 3 * (size_t)XSZ + 3 * (size_t)WSZ) { src = Wv; off = i - 3 * (size_t)XSZ - 2 * (size_t)WSZ; }
  else                        { src = Wo; off = i - 3 * (size_t)XSZ - 3 * (size_t)WSZ; }
  float4 a = *(const float4*)(src + off);
  float4 b = *(const float4*)(src + off + 4);
  bf16x8 o;
  o[0] = (bf16)(a.x * scale); o[1] = (bf16)(a.y * scale);
  o[2] = (bf16)(a.z * scale); o[3] = (bf16)(a.w * scale);
  o[4] = (bf16)(b.x * scale); o[5] = (bf16)(b.y * scale);
  o[6] = (bf16)(b.z * scale); o[7] = (bf16)(b.w * scale);
  *(bf16x8*)(dst + i) = o;
}

// ---------- NT GEMM core, BK=32 2-phase dbuf: C[128x128] += A[m,:] . B[n,:] ----------
__device__ __forceinline__ void gemm_nt_core(const bf16* __restrict__ A, const bf16* __restrict__ Bm,
                                             int m0, int n0, bf16* lds, f32x4 acc[4][4]) {
  const int t = threadIdx.x;
  const int lane = t & 63, wave = t >> 6;
  const int wm = wave & 1, wn = wave >> 1;
  const int quad = lane >> 4, m16 = lane & 15;
  const bf16* gA[2]; int dstc[2];
  #pragma unroll
  for (int j = 0; j < 2; j++) {
    int c = t + j * 256;               // 0..511
    int row = c >> 2;                  // 0..127
    int col = ((c & 3) ^ (row & 3)) * 8;
    gA[j] = A + (size_t)(m0 + row) * KDIM + col;
    dstc[j] = c * 8;
  }
  const ptrdiff_t dBA = (Bm + (size_t)n0 * KDIM) - (A + (size_t)m0 * KDIM);
  const int swzA = quad ^ (m16 & 3);   // read-side granule
  // prologue: stage K-tile 0 into buf 0
  #pragma unroll
  for (int j = 0; j < 2; j++) {
    async16(gA[j], lds + dstc[j]);
    async16(gA[j] + dBA, lds + 4096 + dstc[j]);
  }
  for (int kt = 0; kt < 32; ++kt) {
    __syncthreads();                   // stage(kt) arrived; buf[nxt] reads done
    const int cur = (kt & 1) * 8192;
    if (kt + 1 < 32) {
      const int nxt = 8192 - cur;
      #pragma unroll
      for (int j = 0; j < 2; j++) {
        async16(gA[j] + (kt + 1) * 32, lds + nxt + dstc[j]);
        async16(gA[j] + dBA + (kt + 1) * 32, lds + nxt + 4096 + dstc[j]);
      }
    }
    const bf16* As = lds + cur;
    const bf16* Bs = As + 4096;
    bf16x8 af[4], bfv[4];
    #pragma unroll
    for (int i = 0; i < 4; i++)
      af[i] = ld16(As + (wm * 64 + i * 16 + m16) * 32 + swzA * 8);
    #pragma unroll
    for (int i = 0; i < 4; i++)
      bfv[i] = ld16(Bs + (wn * 64 + i * 16 + m16) * 32 + swzA * 8);
    #pragma unroll
    for (int mi = 0; mi < 4; mi++)
      #pragma unroll
      for (int ni = 0; ni < 4; ni++)
        acc[mi][ni] = mfma16(af[mi], bfv[ni], acc[mi][ni]);
  }
}

// ---------- fused Q/K/V projection ----------
__global__ __launch_bounds__(256, 4) void proj_gemm(const bf16* __restrict__ xq, const bf16* __restrict__ xk,
                                                 const bf16* __restrict__ xv, const bf16* __restrict__ wq,
                                                 const bf16* __restrict__ wk, const bf16* __restrict__ wv,
                                                 bf16* __restrict__ Qo, bf16* __restrict__ Ko,
                                                 bf16* __restrict__ Vo) {
  __shared__ __align__(16) bf16 lds[2 * 8192];   // 32 KB (2 bufs x (A+B))
  const int z = blockIdx.z;
  const bf16* A = (z == 0) ? xq : (z == 1) ? xk : xv;
  const bf16* W = (z == 0) ? wq : (z == 1) ? wk : wv;
  bf16* C = (z == 0) ? Qo : (z == 1) ? Ko : Vo;
  f32x4 acc[4][4];
  #pragma unroll
  for (int i = 0; i < 4; i++)
    #pragma unroll
    for (int j = 0; j < 4; j++) acc[i][j] = (f32x4){0.f, 0.f, 0.f, 0.f};
  gemm_nt_core(A, W, blockIdx.y * 128, blockIdx.x * 128, lds, acc);
  const int lane = threadIdx.x & 63, wave = threadIdx.x >> 6;
  const int wm = wave & 1, wn = wave >> 1, quad = lane >> 4, m16 = lane & 15;
  const int row0 = blockIdx.y * 128 + wm * 64;
  const int col0 = blockIdx.x * 128 + wn * 64;
  #pragma unroll
  for (int mi = 0; mi < 4; mi++)
    #pragma unroll
    for (int ni = 0; ni < 4; ni++)
      #pragma unroll
      for (int r = 0; r < 4; r++) {
        int row = row0 + mi * 16 + quad * 4 + r;
        int col = col0 + ni * 16 + m16;
        C[(size_t)row * 1024 + col] = (bf16)acc[mi][ni][r];
      }
}

// ---------- output projection: 64x64 tiles (grid (16,64) = 1024 = 4/CU) ----------
// R23: was 128x64 at 512 blocks = 2 blocks/CU = 2 waves/SIMD. 64x64 at 1024
// blocks = 4 blocks/CU = 4 waves/SIMD; HBM traffic identical (A 128 MB, B
// 64 MB either way). 4 waves, wave tile 32x32, acc[2][2]. LDS 16 KB
// (2 bufs x (A 4KB + B 4KB)). Same BK=32 2-phase core pattern, same K-order.
__global__ __launch_bounds__(256, 4) void out_gemm(const bf16* __restrict__ Hm, const bf16* __restrict__ wo,
                                                const float* __restrict__ bias, float* __restrict__ out) {
  __shared__ __align__(16) bf16 lds[2 * 4096];   // 16 KB
  const int t = threadIdx.x;
  const int lane = t & 63, wave = t >> 6;
  const int wm = wave & 1, wn = wave >> 1;
  const int quad = lane >> 4, m16 = lane & 15;
  const int m0 = blockIdx.y * 64, n0 = blockIdx.x * 64;
  // A: 64x32 = 256 chunks (1/thread); B: 64x32 = 256 chunks (1/thread)
  const bf16* gA; const bf16* gB; int dstc;
  {
    int c = t;                       // 0..255
    int row = c >> 2;                // 0..63
    int col = ((c & 3) ^ (row & 3)) * 8;
    gA = Hm + (size_t)(m0 + row) * KDIM + col;
    gB = wo + (size_t)(n0 + row) * KDIM + col;
    dstc = c * 8;
  }
  const int swzA = quad ^ (m16 & 3);
  f32x4 acc[2][2];
  #pragma unroll
  for (int i = 0; i < 2; i++)
    #pragma unroll
    for (int j = 0; j < 2; j++) acc[i][j] = (f32x4){0.f, 0.f, 0.f, 0.f};
  // prologue: stage K-tile 0 into buf 0 (A at 0, B at 2048 elems)
  async16(gA, lds + dstc);
  async16(gB, lds + 2048 + dstc);
  for (int kt = 0; kt < 32; ++kt) {
    __syncthreads();
    const int cur = (kt & 1) * 4096;
    if (kt + 1 < 32) {
      const int nxt = 4096 - cur;
      async16(gA + (kt + 1) * 32, lds + nxt + dstc);
      async16(gB + (kt + 1) * 32, lds + nxt + 2048 + dstc);
    }
    const bf16* As = lds + cur;
    const bf16* Bs = As + 2048;
    bf16x8 af[2], bfv[2];
    #pragma unroll
    for (int i = 0; i < 2; i++)
      af[i] = ld16(As + (wm * 32 + i * 16 + m16) * 32 + swzA * 8);
    #pragma unroll
    for (int i = 0; i < 2; i++)
      bfv[i] = ld16(Bs + (wn * 32 + i * 16 + m16) * 32 + swzA * 8);
    #pragma unroll
    for (int mi = 0; mi < 2; mi++)
      #pragma unroll
      for (int ni = 0; ni < 2; ni++)
        acc[mi][ni] = mfma16(af[mi], bfv[ni], acc[mi][ni]);
  }
  const int row0 = m0 + wm * 32;
  const int col0 = n0 + wn * 32;
  float bv[2];
  #pragma unroll
  for (int ni = 0; ni < 2; ni++) bv[ni] = bias[col0 + ni * 16 + m16];
  #pragma unroll
  for (int mi = 0; mi < 2; mi++)
    #pragma unroll
    for (int ni = 0; ni < 2; ni++)
      #pragma unroll
      for (int r = 0; r < 4; r++) {
        int row = row0 + mi * 16 + quad * 4 + r;
        int col = col0 + ni * 16 + m16;
        out[(size_t)row * 1024 + col] = acc[mi][ni][r] + bv[ni];
      }
}

// ---------- V transpose per head-chunk: V[2048][64] -> Vt[64][2048] ----------
__global__ __launch_bounds__(256) void transpose_v(const bf16* __restrict__ V, bf16* __restrict__ Vt) {
  __shared__ bf16 T[64 * 65];
  const int t = threadIdx.x;
  const bf16* src = V + (size_t)blockIdx.y * (2048 * 64) + (size_t)blockIdx.x * 64 * 64;
  bf16* dst = Vt + (size_t)blockIdx.y * (2048 * 64) + (size_t)blockIdx.x * 64;
  #pragma unroll
  for (int j = 0; j < 2; j++) {
    int c = t + j * 256;
    int row = c >> 3, col8 = (c & 7) * 8;
    bf16x8 v = *(const bf16x8*)(src + row * 64 + col8);
    #pragma unroll
    for (int i = 0; i < 8; i++) T[row * 65 + col8 + i] = v[i];
  }
  __syncthreads();
  #pragma unroll
  for (int j = 0; j < 2; j++) {
    int c = t + j * 256;
    int d = c >> 3, k8 = (c & 7) * 8;
    bf16x8 o;
    #pragma unroll
    for (int i = 0; i < 8; i++) o[i] = T[(k8 + i) * 65 + d];
    *(bf16x8*)(dst + (size_t)d * 2048 + k8) = o;
  }
}

// ---------- flash attention: S^T/32x32 MFMA, no-max exp2 softmax, FULL-SEQ ----------
// R15 structure verbatim (best measured: 73.0-76.5us). In-block key-split (512
// threads = 8 waves; waves 0-3 keys 0..1023, waves 4-7 keys 1024..2047, same
// 128 queries). global_load_lds staging (linear LDS, XOR-pre-swizzled global
// source, XOR on read) + 64-key sub-tile double-buffer, ONE barrier per
// sub-tile. LDS 64 KB -> 2 blocks/CU (grid 512 = 2/CU is binding anyway, R19).
__global__ __launch_bounds__(512, 2) void attn_kernel(const bf16* __restrict__ Qg,
                                                      const bf16* __restrict__ Kg,
                                                      const bf16* __restrict__ Vtg,
                                                      bf16* __restrict__ Hout) {
  __shared__ __align__(16) bf16 smem[32768];  // 64 KB
  const int t = threadIdx.x;
  const int lane = t & 63;
  const int w = (t >> 6) & 3;       // wave within key-half (owns q-rows w*32..)
  const int half = t >> 8;          // 0: keys 0..1023, 1: keys 1024..2047
  const int tt = t & 255;           // staging thread id within half
  const int l31 = lane & 31, h = lane >> 5, l7 = lane & 7;
  bf16* hb = smem + half * 16384;   // this half's 32 KB (2 bufs x 16 KB)
  // XCD-pinned swizzle: L%8 = XCD (dispatch round-robin heuristic; perf-only)
  const int L = blockIdx.x + 16 * blockIdx.y;   // 0..511
  const int xcd = L & 7, j5 = L >> 3;           // j5: 0..63
  const int bh = xcd * 4 + (j5 & 3);            // 4 heads per XCD
  const int qt = j5 >> 2;                       // 0..15
  const size_t base = (size_t)bh * (2048 * 64);
  const bf16* Kp = Kg + base;
  const bf16* Vp = Vtg + base;                  // V^T rows stride 2048
  const int q = qt * 128 + w * 32 + l31;        // this lane's q-column

  // Q fragments (B-operand: n=l31, k=16kc+8h+j) in registers for the whole loop
  bf16x8 qf[4];
  #pragma unroll
  for (int kc = 0; kc < 4; kc++)
    qf[kc] = *(const bf16x8*)(Qg + base + (size_t)q * 64 + 16 * kc + 8 * h);

  f32x16 oacc[2];
  #pragma unroll
  for (int mt = 0; mt < 2; mt++)
    #pragma unroll
    for (int i = 0; i < 16; i++) oacc[mt][i] = 0.f;
  float lrow = 0.f;

  // staging geometry: per sub-tile each thread stages 2 K-chunks + 2 V-chunks
  // (16B each). LDS dst linear (c*8 elems); global source column pre-swizzled
  // by ((c&7)^(row&7))*8 so the XOR-read below lands on the right data.
  const bf16* ksrc[2]; const bf16* vsrc[2]; int dstc[2];
  #pragma unroll
  for (int j = 0; j < 2; j++) {
    int c = tt + j * 256;
    int row = c >> 3;                 // 0..63
    int sw = ((c & 7) ^ (row & 7)) * 8;
    ksrc[j] = Kp + (size_t)(half * 1024 + row) * 64 + sw;   // + st*4096 per sub-tile
    vsrc[j] = Vp + (size_t)row * 2048 + half * 1024 + sw;   // + st*64 per sub-tile
    dstc[j] = c * 8;
  }

  // prologue: stage sub-tile 0 into buf 0
  #pragma unroll
  for (int j = 0; j < 2; j++) {
    async16(ksrc[j], hb + dstc[j]);
    async16(vsrc[j], hb + 4096 + dstc[j]);
  }

  for (int st = 0; st < 16; ++st) {
    __syncthreads();   // stage(st) arrived (vmcnt drained) AND buf[(st+1)&1] free
    const int buf = st & 1;
    if (st + 1 < 16) {
      const int nb = (buf ^ 1) * 8192;
      #pragma unroll
      for (int j = 0; j < 2; j++) {
        async16(ksrc[j] + (st + 1) * 4096, hb + nb + dstc[j]);
        async16(vsrc[j] + (st + 1) * 64,   hb + nb + 4096 + dstc[j]);
      }
    }
    bf16* Kb = hb + buf * 8192;
    bf16* Vb = Kb + 4096;

    // two 32-key groups per 64-key sub-tile
    #pragma unroll
    for (int mtq = 0; mtq < 2; mtq++) {
      f32x16 sacc;
      #pragma unroll
      for (int i = 0; i < 16; i++) sacc[i] = 0.f;
      #pragma unroll
      for (int kc = 0; kc < 4; kc++) {
        bf16x8 kf = ld16(Kb + (32 * mtq + l31) * 64 + (((2 * kc + h) ^ l7) << 3));
        sacc = mfma32(kf, qf[kc], sacc);
      }
      int pd[8];
      float sum = 0.f;
      #pragma unroll
      for (int p = 0; p < 8; p++) {
        float p0 = fast_exp2(sacc[2 * p]);
        float p1 = fast_exp2(sacc[2 * p + 1]);
        sum += p0 + p1;
        pd[p] = packbf2(p0, p1);
      }
      lrow += sum;
      // O^T += V^T . P^T for this group's two 16-key chunks
      #pragma unroll
      for (int c1 = 0; c1 < 2; c1++) {
        const int kcp = 2 * mtq + c1;
        const int rro = 2 * c1 + h;        // own reg-group
        const int rrp = 2 * c1 + 1 - h;    // what the partner half needs from us
        int s0 = __shfl_xor(pd[2 * rrp], 32, 64);
        int s1 = __shfl_xor(pd[2 * rrp + 1], 32, 64);
        int o0 = pd[2 * rro], o1 = pd[2 * rro + 1];
        i32x4 w4;
        w4.x = h ? s0 : o0;
        w4.y = h ? s1 : o1;
        w4.z = h ? o0 : s0;
        w4.w = h ? o1 : s1;
        bf16x8 pfrag = __builtin_bit_cast(bf16x8, w4);
        #pragma unroll
        for (int mtd = 0; mtd < 2; mtd++) {
          bf16x8 vf = ld16(Vb + (32 * mtd + l31) * 64 + (((2 * kcp + h) ^ l7) << 3));
          oacc[mtd] = mfma32(vf, pfrag, oacc[mtd]);
        }
      }
    }
  }
  __syncthreads();   // all LDS reads done before epilogue reuses smem

  // epilogue: in-block merge of the two key-halves, normalize, transpose
  // O^T -> O[q][d] through LDS, store bf16 H. Wave-pair (w, half=0/1) shares an
  // 8 KB fp32 region: half1 deposits unnormalized O^T + l, half0 adds its own,
  // normalizes, writes back; then all 8 waves cooperatively store bf16.
  lrow += __shfl_xor(lrow, 32, 64);
  float* Sf = (float*)smem;
  float* Tf = Sf + w * 2048;        // [64 d][32 q] per wave-pair
  float* Lb = Sf + 8192 + w * 32;   // l partials, one row per wave-pair
  if (half) {
    #pragma unroll
    for (int mt = 0; mt < 2; mt++)
      #pragma unroll
      for (int r = 0; r < 16; r++) {
        int d = 32 * mt + (r & 3) + 8 * (r >> 2) + 4 * h;
        Tf[d * 32 + l31] = oacc[mt][r];
      }
    if (!h) Lb[l31] = lrow;
  }
  __syncthreads();
  if (!half) {
    float linv = 1.f / (lrow + Lb[l31]);
    #pragma unroll
    for (int mt = 0; mt < 2; mt++)
      #pragma unroll
      for (int r = 0; r < 16; r++) {
        int d = 32 * mt + (r & 3) + 8 * (r >> 2) + 4 * h;
        Tf[d * 32 + l31] = (oacc[mt][r] + Tf[d * 32 + l31]) * linv;
      }
  }
  __syncthreads();
  bf16* Hq = Hout + base + (size_t)(qt * 128 + w * 32 + l31) * 64 + 32 * h;
  #pragma unroll
  for (int s = 0; s < 2; s++) {
    int se = half * 2 + s;           // each half stores 2 of the 4 d-octets
    bf16x8 o;
    #pragma unroll
    for (int i = 0; i < 8; i++) o[i] = (bf16)Tf[(32 * h + se * 8 + i) * 32 + l31];
    *(bf16x8*)(Hq + se * 8) = o;
  }
}

// ---------- launch ----------
extern "C" void kernel_launch(void* const* d_in, const int* in_sizes, int n_in,
                              void* d_out, int out_size, void* d_ws, size_t ws_size,
                              hipStream_t stream) {
  const float* Xq = (const float*)d_in[0];
  const float* Xk = (const float*)d_in[1];
  const float* Xv = (const float*)d_in[2];
  const float* Wq = (const float*)d_in[3];
  const float* Wk = (const float*)d_in[4];
  const float* Wv = (const float*)d_in[5];
  const float* Wo = (const float*)d_in[6];
  const float* bo = (const float*)d_in[7];

  bf16* ws = (bf16*)d_ws;
  bf16* xq = ws;                 // casts write [xq xk xv wq wk wv wo] contiguously
  bf16* xk = ws + XSZ;
  bf16* xv = ws + 2 * (size_t)XSZ;
  bf16* wq = ws + 3 * (size_t)XSZ;
  bf16* wk = wq + WSZ;
  bf16* wv = wk + WSZ;
  bf16* wo = wv + WSZ;
  bf16* q  = wo + WSZ;
  bf16* k  = q + XSZ;
  bf16* v  = k + XSZ;
  bf16* vt = xv;                 // alias: X_v dead after projection
  bf16* h  = xq;                 // alias: X_q dead after projection

  cast_all<<<8192, 256, 0, stream>>>(Xq, Xk, Xv, Wq, Wk, Wv, Wo, ws);
  proj_gemm<<<dim3(8, 32, 3), 256, 0, stream>>>(xq, xk, xv, wq, wk, wv, q, k, v);
  transpose_v<<<dim3(32, 32), 256, 0, stream>>>(v, vt);
  attn_kernel<<<dim3(16, 32), 512, 0, stream>>>(q, k, vt, h);
  out_gemm<<<dim3(16, 64), 256, 0, stream>>>(h, wo, bo, (float*)d_out);
}